// Round 5
// baseline (150.416 us; speedup 1.0000x reference)
//
#include <hip/hip_runtime.h>

// Encoding layer, fused. B=32, C=256, K=32, N=4096.
// R5: 1024 blocks x 128 tokens, 2 threads/token in pass A, ~25 KB LDS, 4 blocks/CU resident.
// ws layout (floats): wx[262144] @0 | wsum[1024] @262144 | abp4[128] @263168 | cw2t[4096 u32] @263296

#define CC 256
#define KK 32
#define NN 4096
#define CN (CC*NN)
#define TOK 128    // tokens per block
#define TPB 256    // threads per block

typedef unsigned int u32;
typedef unsigned short u16;
typedef __fp16 half2_t __attribute__((ext_vector_type(2)));

__device__ __forceinline__ u32 pack2(float a, float b) {
    half2_t h = __builtin_amdgcn_cvt_pkrtz(a, b);
    u32 u;
    __builtin_memcpy(&u, &h, 4);
    return u;
}

__device__ __forceinline__ float fdot2u(u32 a, u32 b, float c) {
    half2_t ha, hb;
    __builtin_memcpy(&ha, &a, 4);
    __builtin_memcpy(&hb, &b, 4);
#if __has_builtin(__builtin_amdgcn_fdot2)
    return __builtin_amdgcn_fdot2(ha, hb, c, false);
#else
    return c + (float)ha[0] * (float)hb[0] + (float)ha[1] * (float)hb[1];
#endif
}

// ---------------- prep: per-k logit constants + fp16-pair-packed codewords [cp][k] ----------------
__global__ void enc_prep(const float* __restrict__ cw, const float* __restrict__ scale,
                         float* __restrict__ abp4, u32* __restrict__ cw2t) {
    int tid = threadIdx.x;
    {
        int k = tid >> 3, p = tid & 7;
        float s = 0.f;
        #pragma unroll
        for (int i = 0; i < 32; ++i) {
            float v = cw[k * 256 + p * 32 + i];
            s += v * v;
        }
        s += __shfl_xor(s, 1);
        s += __shfl_xor(s, 2);
        s += __shfl_xor(s, 4);
        if (p == 0) {
            float A = scale[k];
            abp4[k * 4 + 0] = A;          // A_k
            abp4[k * 4 + 1] = A * s;      // A_k * csq_k
            abp4[k * 4 + 2] = -2.f * A;   // P_k
            abp4[k * 4 + 3] = 0.f;
        }
    }
    for (int it = 0; it < 16; ++it) {
        int idx = it * 256 + tid;
        int cp = idx >> 5, k = idx & 31;
        cw2t[idx] = pack2(cw[k * 256 + 2 * cp], cw[k * 256 + 2 * cp + 1]);
    }
}

// ---------------- fused main: 1024 blocks x 256 threads, 128 tokens each ----------------
// LDS: region0 = max(sc[128*32]f32 + sx[128]f32 = 16896B, xt[16*258]u32 = 16512B) = 4224 u32
//      w2s u16[32*128] = 2048 u32.  Total 6272 u32 = 25088 B -> 6 blocks/CU by LDS.
__global__ __launch_bounds__(256) void enc_main(
    const float* __restrict__ x, const u32* __restrict__ cw2t,
    const float* __restrict__ abp4, float* __restrict__ wx, float* __restrict__ wsum) {

    __shared__ u32 smem[6272];
    float* sc = (float*)smem;            // [128][32] f32, XOR-swizzled
    float* sx = (float*)smem + 4096;     // [128] f32
    u32*   xt = smem;                    // [16][258] u32 (overlays sc; disjoint in time)
    u16*   w2s = (u16*)(smem + 4224);    // [32][128] u16

    const int tid = threadIdx.x;
    const int l   = tid & 63;
    const int h   = tid >> 7;            // channel-half (wave-uniform)
    const int t   = tid & 127;           // token within block
    const int b   = blockIdx.x >> 5;
    const int blk = blockIdx.x & 31;
    const int n0  = blk * TOK;
    const int wu  = __builtin_amdgcn_readfirstlane(tid >> 6);

    // ================= pass A: thread = (half, token), 128 channels each =================
    const float* xg = x + (size_t)b * CN + (size_t)(h * 128) * NN + n0 + t;
    float xc[32];
    #pragma unroll
    for (int k = 0; k < 32; ++k) xc[k] = 0.f;
    float xsq = 0.f;

    float va[16], vb[16];
    #pragma unroll
    for (int j = 0; j < 16; ++j) va[j] = xg[(size_t)j * NN];

    #define CONSUME(V, BB)                                                     \
        {                                                                      \
            _Pragma("unroll")                                                  \
            for (int i = 0; i < 8; ++i) {                                      \
                float v0 = V[2 * i], v1 = V[2 * i + 1];                        \
                xsq += v0 * v0 + v1 * v1;                                      \
                u32 xv = pack2(v0, v1);                                        \
                const u32* cwr = cw2t + (h * 64 + (BB) * 8 + i) * 32;          \
                _Pragma("unroll")                                              \
                for (int k = 0; k < 32; ++k)                                   \
                    xc[k] = fdot2u(xv, cwr[k], xc[k]);                         \
            }                                                                  \
        }

    for (int bb = 0; bb < 8; bb += 2) {
        #pragma unroll
        for (int j = 0; j < 16; ++j) vb[j] = xg[(size_t)((bb + 1) * 16 + j) * NN];
        CONSUME(va, bb);
        if (bb < 6) {
            #pragma unroll
            for (int j = 0; j < 16; ++j) va[j] = xg[(size_t)((bb + 2) * 16 + j) * NN];
        }
        CONSUME(vb, bb + 1);
    }
    #undef CONSUME

    // ================= exchange half-1 partials -> half-0 =================
    if (h == 1) {
        int xr = (t & 7) << 2;
        #pragma unroll
        for (int g = 0; g < 8; ++g) {
            float4 v = make_float4(xc[g * 4], xc[g * 4 + 1], xc[g * 4 + 2], xc[g * 4 + 3]);
            *(float4*)&sc[t * 32 + ((g * 4) ^ xr)] = v;
        }
        sx[t] = xsq;
    }
    __syncthreads();  // bar1

    // ================= softmax on half-0 threads (waves 0,1) =================
    if (h == 0) {
        int xr = (t & 7) << 2;
        #pragma unroll
        for (int g = 0; g < 8; ++g) {
            float4 v = *(const float4*)&sc[t * 32 + ((g * 4) ^ xr)];
            xc[g * 4]     += v.x;
            xc[g * 4 + 1] += v.y;
            xc[g * 4 + 2] += v.z;
            xc[g * 4 + 3] += v.w;
        }
        xsq += sx[t];
        const float4* ap = (const float4*)abp4;
        float m = -3.4e38f;
        #pragma unroll
        for (int k = 0; k < 32; ++k) {
            float4 tt = ap[k];
            xc[k] = fmaf(tt.x, xsq, tt.y) + tt.z * xc[k];
            m = fmaxf(m, xc[k]);
        }
        float s = 0.f;
        #pragma unroll
        for (int k = 0; k < 32; ++k) { xc[k] = __expf(xc[k] - m); s += xc[k]; }
        float r = 1.0f / s;
        #pragma unroll
        for (int k = 0; k < 32; ++k) {
            union { __fp16 hh; u16 us; } cv;
            cv.hh = (__fp16)(xc[k] * r);
            w2s[k * TOK + t] = cv.us;
        }
    }
    __syncthreads();  // bar2: w2s ready

    // ================= wsum: 8 lanes x 16 tokens per k =================
    {
        int k = tid >> 3, seg = tid & 7;
        const uint4* wp = (const uint4*)&w2s[k * TOK + seg * 16];
        uint4 a0 = wp[0], a1 = wp[1];  // 16 tokens
        const u32 ONES = 0x3C003C00u;
        float s = 0.f;
        s = fdot2u(a0.x, ONES, s); s = fdot2u(a0.y, ONES, s);
        s = fdot2u(a0.z, ONES, s); s = fdot2u(a0.w, ONES, s);
        s = fdot2u(a1.x, ONES, s); s = fdot2u(a1.y, ONES, s);
        s = fdot2u(a1.z, ONES, s); s = fdot2u(a1.w, ONES, s);
        s += __shfl_xor(s, 1);
        s += __shfl_xor(s, 2);
        s += __shfl_xor(s, 4);
        if (seg == 0) atomicAdd(&wsum[b * KK + k], s);
    }

    // ================= pass B: 4 sub-chunks of 32 tokens =================
    float acc[8][4];
    #pragma unroll
    for (int j = 0; j < 8; ++j)
        #pragma unroll
        for (int q = 0; q < 4; ++q) acc[j][q] = 0.f;

    for (int s = 0; s < 4; ++s) {
        const int t0 = s * 32;
        __syncthreads();  // previous consume done before overwriting xt (also spaces bar2)
        // stage: item = (c, tp): c = it*16 + (tid>>4), tp = tid&15
        #pragma unroll
        for (int it = 0; it < 16; ++it) {
            int c = it * 16 + (tid >> 4), tp = tid & 15;
            const float2* xs = (const float2*)(x + (size_t)b * CN + (size_t)c * NN + n0 + t0);
            float2 v = xs[tp];
            xt[tp * 258 + c] = pack2(v.x, v.y);
        }
        __syncthreads();  // xt ready

        #pragma unroll
        for (int tg = 0; tg < 4; ++tg) {
            uint4 wf[8];
            #pragma unroll
            for (int j = 0; j < 8; ++j)
                wf[j] = *(const uint4*)&w2s[(wu * 8 + j) * TOK + t0 + tg * 8];  // broadcast
            #pragma unroll
            for (int q = 0; q < 4; ++q) {
                int c = l + 64 * q;
                u32 x0 = xt[(tg * 4 + 0) * 258 + c];
                u32 x1 = xt[(tg * 4 + 1) * 258 + c];
                u32 x2 = xt[(tg * 4 + 2) * 258 + c];
                u32 x3 = xt[(tg * 4 + 3) * 258 + c];
                #pragma unroll
                for (int j = 0; j < 8; ++j) {
                    acc[j][q] = fdot2u(x0, wf[j].x, acc[j][q]);
                    acc[j][q] = fdot2u(x1, wf[j].y, acc[j][q]);
                    acc[j][q] = fdot2u(x2, wf[j].z, acc[j][q]);
                    acc[j][q] = fdot2u(x3, wf[j].w, acc[j][q]);
                }
            }
        }
    }

    // ================= epilogue: wx atomics =================
    #pragma unroll
    for (int j = 0; j < 8; ++j)
        #pragma unroll
        for (int q = 0; q < 4; ++q)
            atomicAdd(&wx[(size_t)b * 8192 + (wu * 8 + j) * 256 + (l + 64 * q)], acc[j][q]);
}

// ---------------- finalize: out = wx - wsum*c ----------------
__global__ void enc_final(const float* __restrict__ wx, const float* __restrict__ wsum,
                          const float* __restrict__ cw, float* __restrict__ out) {
    int i = blockIdx.x * 256 + threadIdx.x;
    int c = i & 255, k = (i >> 8) & 31, b = i >> 13;
    out[i] = wx[i] - wsum[b * 32 + k] * cw[k * 256 + c];
}

extern "C" void kernel_launch(void* const* d_in, const int* in_sizes, int n_in,
                              void* d_out, int out_size, void* d_ws, size_t ws_size,
                              hipStream_t stream) {
    (void)in_sizes; (void)n_in; (void)out_size; (void)ws_size;
    const float* x     = (const float*)d_in[0];
    const float* cw    = (const float*)d_in[1];
    const float* scale = (const float*)d_in[2];
    float* out = (float*)d_out;

    float* wsf   = (float*)d_ws;
    float* wx    = wsf;                  // 262144 f32
    float* wsum  = wsf + 262144;         // 1024 f32
    float* abp4  = wsf + 263168;         // 128 f32
    u32*   cw2t  = (u32*)(wsf + 263296); // 4096 u32

    (void)hipMemsetAsync(d_ws, 0, 263168 * sizeof(float), stream);  // zero wx + wsum
    hipLaunchKernelGGL(enc_prep,  dim3(1),    dim3(256), 0, stream, cw, scale, abp4, cw2t);
    hipLaunchKernelGGL(enc_main,  dim3(1024), dim3(256), 0, stream, x, cw2t, abp4, wx, wsum);
    hipLaunchKernelGGL(enc_final, dim3(1024), dim3(256), 0, stream, wx, wsum, cw, out);
}

// Round 6
// 79.777 us; speedup vs baseline: 1.8855x; 1.8855x over previous
//
#include <hip/hip_runtime.h>

// Encoding layer, fused, MFMA version. B=32, C=256, K=32, N=4096.
// R6: both GEMMs on matrix cores; x staged once per chunk into subtiled LDS
// serving tr_read (pass A) and row b128 (pass B).
// ws layout: wx[262144]f32 @0 | wsum[1024] @262144 | abp4[128] @263168 | cwh[8192 u16] @263296

#define CC 256
#define KK 32
#define NN 4096
#define CN (CC*NN)
#define TOK 128
#define CHK 32
#define NCH 4

typedef unsigned int u32;
typedef unsigned short u16;
typedef __fp16 half2_t __attribute__((ext_vector_type(2)));
typedef _Float16 f16x8 __attribute__((ext_vector_type(8)));
typedef float f32x4 __attribute__((ext_vector_type(4)));
typedef u32 u32x2 __attribute__((ext_vector_type(2)));

__device__ __forceinline__ u32 pack2(float a, float b) {
    half2_t h = __builtin_amdgcn_cvt_pkrtz(a, b);
    u32 u;
    __builtin_memcpy(&u, &h, 4);
    return u;
}

// ---------------- prep: abp table + fp16 codewords [k][ch] ----------------
__global__ void enc_prep(const float* __restrict__ cw, const float* __restrict__ scale,
                         float* __restrict__ abp4, u16* __restrict__ cwh) {
    int tid = threadIdx.x;
    {
        int k = tid >> 3, p = tid & 7;
        float s = 0.f;
        #pragma unroll
        for (int i = 0; i < 32; ++i) {
            float v = cw[k * 256 + p * 32 + i];
            s += v * v;
        }
        s += __shfl_xor(s, 1);
        s += __shfl_xor(s, 2);
        s += __shfl_xor(s, 4);
        if (p == 0) {
            float A = scale[k];
            abp4[k * 4 + 0] = A;
            abp4[k * 4 + 1] = A * s;
            abp4[k * 4 + 2] = -2.f * A;
            abp4[k * 4 + 3] = 0.f;
        }
    }
    for (int i = 0; i < 32; ++i) {
        int idx = i * 256 + tid;           // [k][ch] row-major
        union { __fp16 h; u16 u; } cv;
        cv.h = (__fp16)cw[idx];
        cwh[idx] = cv.u;
    }
}

// ---------------- fused main: 1024 blocks x 256 threads, 128 tokens each ----------------
__global__ __launch_bounds__(256, 3) void enc_main(
    const float* __restrict__ x, const u16* __restrict__ cwh,
    const float* __restrict__ abp4, float* __restrict__ wx, float* __restrict__ wsum) {

    // xt subtile layout (per buf, per chunk of 32 tok):
    //   f16 index = ((ch>>2)*2 + (tok>>4))*64 + (ch&3)*16 + (tok&15)
    __shared__ u16   xt[2][8192];     // 2 x 16 KB
    __shared__ float sc[32 * 33];     // S exchange [tok][k], stride 33
    __shared__ u16   w2s[32 * 40];    // w fp16 [k][tok], stride 40 (16B-aligned rows)
    __shared__ float swsq[128];       // [wave][32] xsq partials

    const int tid = threadIdx.x;
    const int l   = tid & 63;
    const int w   = tid >> 6;
    const int b   = blockIdx.x >> 5;
    const int blk = blockIdx.x & 31;
    const int n0  = blk * TOK;

    // resident: cw B-frags for pass A (wave's k-tile = w>>1), 8 k-steps
    f16x8 cwf[8];
    {
        const u16* cp = cwh + ((w >> 1) * 16 + (l & 15)) * 256 + (l >> 4) * 8;
        #pragma unroll
        for (int ks = 0; ks < 8; ++ks)
            cwf[ks] = *(const f16x8*)(cp + ks * 32);
    }
    // resident: softmax per-k constants (lane handles k = (l&7)*4 + i)
    float Ak[4], Bk[4], Pk[4];
    #pragma unroll
    for (int i = 0; i < 4; ++i) {
        const float* ap = abp4 + ((l & 7) * 4 + i) * 4;
        Ak[i] = ap[0]; Bk[i] = ap[1]; Pk[i] = ap[2];
    }

    f32x4 accb[2][4];
    #pragma unroll
    for (int mt = 0; mt < 2; ++mt)
        #pragma unroll
        for (int nt = 0; nt < 4; ++nt)
            accb[mt][nt] = (f32x4){0.f, 0.f, 0.f, 0.f};
    float wsacc[4] = {0.f, 0.f, 0.f, 0.f};

    const u32 xtbase = (u32)(uintptr_t)(&xt[0][0]);
    float4 sf[8];

    #define STAGE_LOAD(CT) {                                                   \
        const float* xp = x + (size_t)b * CN + n0 + (CT) * CHK + (l & 7) * 4;  \
        _Pragma("unroll")                                                      \
        for (int it = 0; it < 8; ++it) {                                       \
            int ch = it * 32 + w * 8 + (l >> 3);                               \
            sf[it] = *(const float4*)(xp + (size_t)ch * NN);                   \
        }                                                                      \
    }
    #define STAGE_WRITE(BUF) {                                                 \
        float s0 = 0.f, s1 = 0.f, s2 = 0.f, s3 = 0.f;                          \
        int tq = l & 7;                                                        \
        _Pragma("unroll")                                                      \
        for (int it = 0; it < 8; ++it) {                                       \
            int ch = it * 32 + w * 8 + (l >> 3);                               \
            float4 f = sf[it];                                                 \
            s0 += f.x * f.x; s1 += f.y * f.y;                                  \
            s2 += f.z * f.z; s3 += f.w * f.w;                                  \
            u32 u0 = pack2(f.x, f.y), u1 = pack2(f.z, f.w);                    \
            *(uint2*)(&xt[BUF][((ch >> 2) * 2 + (tq >> 2)) * 64 +              \
                               (ch & 3) * 16 + (tq & 3) * 4]) =                \
                make_uint2(u0, u1);                                            \
        }                                                                      \
        s0 += __shfl_xor(s0, 8); s0 += __shfl_xor(s0, 16); s0 += __shfl_xor(s0, 32); \
        s1 += __shfl_xor(s1, 8); s1 += __shfl_xor(s1, 16); s1 += __shfl_xor(s1, 32); \
        s2 += __shfl_xor(s2, 8); s2 += __shfl_xor(s2, 16); s2 += __shfl_xor(s2, 32); \
        s3 += __shfl_xor(s3, 8); s3 += __shfl_xor(s3, 16); s3 += __shfl_xor(s3, 32); \
        if (l < 8) *(float4*)&swsq[w * 32 + tq * 4] = make_float4(s0, s1, s2, s3); \
    }

    // prologue: stage chunk 0
    STAGE_LOAD(0);
    STAGE_WRITE(0);
    __syncthreads();

    #pragma unroll
    for (int ct = 0; ct < NCH; ++ct) {
        const int p = ct & 1;

        // ---- phase 1: issue next-chunk loads, then MFMA-A (S = X·Cw^T) ----
        if (ct < NCH - 1) STAGE_LOAD(ct + 1);

        f32x4 acca = (f32x4){0.f, 0.f, 0.f, 0.f};
        {
            u32 abase = xtbase + p * 16384 +
                        (4 * (l >> 4) + (w & 1)) * 128 + (l & 15) * 8;
            #pragma unroll
            for (int ks = 0; ks < 8; ++ks) {
                u32x2 r1, r2;
                asm volatile("ds_read_b64_tr_b16 %0, %1 offset:%2"
                             : "=v"(r1) : "v"(abase), "i"(ks * 2048));
                asm volatile("ds_read_b64_tr_b16 %0, %1 offset:%2"
                             : "=v"(r2) : "v"(abase), "i"(ks * 2048 + 256));
                asm volatile("s_waitcnt lgkmcnt(0)");
                __builtin_amdgcn_sched_barrier(0);
                union { uint4 u; f16x8 h; } af;
                af.u = make_uint4(r1.x, r1.y, r2.x, r2.y);
                acca = __builtin_amdgcn_mfma_f32_16x16x32_f16(af.h, cwf[ks], acca, 0, 0, 0);
            }
        }
        {   // write S tile: row tok = (w&1)*16 + (l>>4)*4 + r, col k = (w>>1)*16 + (l&15)
            int trow = (w & 1) * 16 + (l >> 4) * 4;
            int kcol = (w >> 1) * 16 + (l & 15);
            #pragma unroll
            for (int r = 0; r < 4; ++r)
                sc[(trow + r) * 33 + kcol] = acca[r];
        }
        __syncthreads();  // bar A: sc + (prev-phase) xt stable

        // ---- phase 2: softmax (all lanes: t = w*8 + (l>>3), k-quad s = l&7) ----
        {
            int t = w * 8 + (l >> 3), s = l & 7;
            float xq = swsq[t] + swsq[32 + t] + swsq[64 + t] + swsq[96 + t];
            float lg[4];
            float m = -3.4e38f;
            #pragma unroll
            for (int i = 0; i < 4; ++i) {
                float xcv = sc[t * 33 + s * 4 + i];
                lg[i] = fmaf(Ak[i], xq, Bk[i]) + Pk[i] * xcv;
                m = fmaxf(m, lg[i]);
            }
            m = fmaxf(m, __shfl_xor(m, 1));
            m = fmaxf(m, __shfl_xor(m, 2));
            m = fmaxf(m, __shfl_xor(m, 4));
            float e[4], ssum = 0.f;
            #pragma unroll
            for (int i = 0; i < 4; ++i) { e[i] = __expf(lg[i] - m); ssum += e[i]; }
            ssum += __shfl_xor(ssum, 1);
            ssum += __shfl_xor(ssum, 2);
            ssum += __shfl_xor(ssum, 4);
            float r = 1.0f / ssum;
            #pragma unroll
            for (int i = 0; i < 4; ++i) {
                float wv = e[i] * r;
                wsacc[i] += wv;
                union { __fp16 h; u16 u; } cv;
                cv.h = (__fp16)wv;
                w2s[(s * 4 + i) * 40 + t] = cv.u;
            }
        }
        __syncthreads();  // bar B: w2s ready

        // ---- phase 3: MFMA-B (wx += W^T·X) + stage-write next chunk ----
        {
            f16x8 wa[2];
            #pragma unroll
            for (int mt = 0; mt < 2; ++mt)
                wa[mt] = *(const f16x8*)&w2s[(mt * 16 + (l & 15)) * 40 + (l >> 4) * 8];
            #pragma unroll
            for (int nt = 0; nt < 4; ++nt) {
                int ch = (w * 4 + nt) * 16 + (l & 15);
                const f16x8 xb = *(const f16x8*)&xt[p][((ch >> 2) * 2 + (l >> 5)) * 64 +
                                                      (ch & 3) * 16 + ((l >> 4) & 1) * 8];
                #pragma unroll
                for (int mt = 0; mt < 2; ++mt)
                    accb[mt][nt] = __builtin_amdgcn_mfma_f32_16x16x32_f16(wa[mt], xb, accb[mt][nt], 0, 0, 0);
            }
        }
        if (ct < NCH - 1) STAGE_WRITE(p ^ 1);
        __syncthreads();  // bar C
    }

    // ---- epilogue ----
    #pragma unroll
    for (int i = 0; i < 4; ++i) {
        float v = wsacc[i];
        v += __shfl_xor(v, 8); v += __shfl_xor(v, 16); v += __shfl_xor(v, 32);
        if (l < 8)
            atomicAdd(&wsum[b * KK + (l & 7) * 4 + i], v);
    }
    #pragma unroll
    for (int mt = 0; mt < 2; ++mt)
        #pragma unroll
        for (int nt = 0; nt < 4; ++nt)
            #pragma unroll
            for (int r = 0; r < 4; ++r) {
                int k  = mt * 16 + (l >> 4) * 4 + r;
                int ch = (w * 4 + nt) * 16 + (l & 15);
                atomicAdd(&wx[(size_t)b * 8192 + k * 256 + ch], accb[mt][nt][r]);
            }
}

// ---------------- finalize: out = wx - wsum*c ----------------
__global__ void enc_final(const float* __restrict__ wx, const float* __restrict__ wsum,
                          const float* __restrict__ cw, float* __restrict__ out) {
    int i = blockIdx.x * 256 + threadIdx.x;
    int c = i & 255, k = (i >> 8) & 31, b = i >> 13;
    out[i] = wx[i] - wsum[b * 32 + k] * cw[k * 256 + c];
}

extern "C" void kernel_launch(void* const* d_in, const int* in_sizes, int n_in,
                              void* d_out, int out_size, void* d_ws, size_t ws_size,
                              hipStream_t stream) {
    (void)in_sizes; (void)n_in; (void)out_size; (void)ws_size;
    const float* x     = (const float*)d_in[0];
    const float* cw    = (const float*)d_in[1];
    const float* scale = (const float*)d_in[2];
    float* out = (float*)d_out;

    float* wsf  = (float*)d_ws;
    float* wxp  = wsf;                   // 262144 f32
    float* wsum = wsf + 262144;          // 1024 f32
    float* abp4 = wsf + 263168;          // 128 f32
    u16*   cwh  = (u16*)(wsf + 263296);  // 8192 u16

    (void)hipMemsetAsync(d_ws, 0, 263168 * sizeof(float), stream);  // zero wx + wsum
    hipLaunchKernelGGL(enc_prep,  dim3(1),    dim3(256), 0, stream, cw, scale, abp4, cwh);
    hipLaunchKernelGGL(enc_main,  dim3(1024), dim3(256), 0, stream, x, cwh, abp4, wxp, wsum);
    hipLaunchKernelGGL(enc_final, dim3(1024), dim3(256), 0, stream, wxp, wsum, cw, out);
}

// Round 7
// 75.230 us; speedup vs baseline: 1.9994x; 1.0604x over previous
//
#include <hip/hip_runtime.h>

// Encoding layer, fused, MFMA version. B=32, C=256, K=32, N=4096.
// R7: wx atomics -> per-block partial stores + reduce in enc_final (ws_size-guarded);
//     phase-1 tr_reads batched before a single lgkmcnt(0).
// ws layout (partial path, floats): wxp[8388608] @0 | wsum[1024] @8388608 | abp4[128] @8389632 | cwh @8389760
// ws layout (fallback,    floats): wx[262144] @0 | wsum[1024] @262144 | abp4[128] @263168 | cwh @263296

#define CC 256
#define KK 32
#define NN 4096
#define CN (CC*NN)
#define TOK 128
#define CHK 32
#define NCH 4

typedef unsigned int u32;
typedef unsigned short u16;
typedef __fp16 half2_t __attribute__((ext_vector_type(2)));
typedef _Float16 f16x8 __attribute__((ext_vector_type(8)));
typedef float f32x4 __attribute__((ext_vector_type(4)));
typedef u32 u32x2 __attribute__((ext_vector_type(2)));

__device__ __forceinline__ u32 pack2(float a, float b) {
    half2_t h = __builtin_amdgcn_cvt_pkrtz(a, b);
    u32 u;
    __builtin_memcpy(&u, &h, 4);
    return u;
}

// ---------------- prep: abp table + fp16 codewords [k][ch] ----------------
__global__ void enc_prep(const float* __restrict__ cw, const float* __restrict__ scale,
                         float* __restrict__ abp4, u16* __restrict__ cwh) {
    int tid = threadIdx.x;
    {
        int k = tid >> 3, p = tid & 7;
        float s = 0.f;
        #pragma unroll
        for (int i = 0; i < 32; ++i) {
            float v = cw[k * 256 + p * 32 + i];
            s += v * v;
        }
        s += __shfl_xor(s, 1);
        s += __shfl_xor(s, 2);
        s += __shfl_xor(s, 4);
        if (p == 0) {
            float A = scale[k];
            abp4[k * 4 + 0] = A;
            abp4[k * 4 + 1] = A * s;
            abp4[k * 4 + 2] = -2.f * A;
            abp4[k * 4 + 3] = 0.f;
        }
    }
    for (int i = 0; i < 32; ++i) {
        int idx = i * 256 + tid;           // [k][ch] row-major
        union { __fp16 h; u16 u; } cv;
        cv.h = (__fp16)cw[idx];
        cwh[idx] = cv.u;
    }
}

// ---------------- fused main: 1024 blocks x 256 threads, 128 tokens each ----------------
__global__ __launch_bounds__(256, 3) void enc_main(
    const float* __restrict__ x, const u16* __restrict__ cwh,
    const float* __restrict__ abp4, float* __restrict__ wxp, float* __restrict__ wsum,
    int use_partials) {

    // xt subtile layout (per buf, per chunk of 32 tok):
    //   f16 index = ((ch>>2)*2 + (tok>>4))*64 + (ch&3)*16 + (tok&15)
    __shared__ u16   xt[2][8192];     // 2 x 16 KB
    __shared__ float sc[32 * 33];     // S exchange [tok][k], stride 33
    __shared__ u16   w2s[32 * 40];    // w fp16 [k][tok], stride 40
    __shared__ float swsq[128];       // [wave][32] xsq partials

    const int tid = threadIdx.x;
    const int l   = tid & 63;
    const int w   = tid >> 6;
    const int b   = blockIdx.x >> 5;
    const int blk = blockIdx.x & 31;
    const int n0  = blk * TOK;

    // resident: cw B-frags for pass A (wave's k-tile = w>>1), 8 k-steps
    f16x8 cwf[8];
    {
        const u16* cp = cwh + ((w >> 1) * 16 + (l & 15)) * 256 + (l >> 4) * 8;
        #pragma unroll
        for (int ks = 0; ks < 8; ++ks)
            cwf[ks] = *(const f16x8*)(cp + ks * 32);
    }
    // resident: softmax per-k constants (lane handles k = (l&7)*4 + i)
    float Ak[4], Bk[4], Pk[4];
    #pragma unroll
    for (int i = 0; i < 4; ++i) {
        const float* ap = abp4 + ((l & 7) * 4 + i) * 4;
        Ak[i] = ap[0]; Bk[i] = ap[1]; Pk[i] = ap[2];
    }

    f32x4 accb[2][4];
    #pragma unroll
    for (int mt = 0; mt < 2; ++mt)
        #pragma unroll
        for (int nt = 0; nt < 4; ++nt)
            accb[mt][nt] = (f32x4){0.f, 0.f, 0.f, 0.f};
    float wsacc[4] = {0.f, 0.f, 0.f, 0.f};

    const u32 xtbase = (u32)(uintptr_t)(&xt[0][0]);
    float4 sf[8];

    #define STAGE_LOAD(CT) {                                                   \
        const float* xp = x + (size_t)b * CN + n0 + (CT) * CHK + (l & 7) * 4;  \
        _Pragma("unroll")                                                      \
        for (int it = 0; it < 8; ++it) {                                       \
            int ch = it * 32 + w * 8 + (l >> 3);                               \
            sf[it] = *(const float4*)(xp + (size_t)ch * NN);                   \
        }                                                                      \
    }
    #define STAGE_WRITE(BUF) {                                                 \
        float s0 = 0.f, s1 = 0.f, s2 = 0.f, s3 = 0.f;                          \
        int tq = l & 7;                                                        \
        _Pragma("unroll")                                                      \
        for (int it = 0; it < 8; ++it) {                                       \
            int ch = it * 32 + w * 8 + (l >> 3);                               \
            float4 f = sf[it];                                                 \
            s0 += f.x * f.x; s1 += f.y * f.y;                                  \
            s2 += f.z * f.z; s3 += f.w * f.w;                                  \
            u32 u0 = pack2(f.x, f.y), u1 = pack2(f.z, f.w);                    \
            *(uint2*)(&xt[BUF][((ch >> 2) * 2 + (tq >> 2)) * 64 +              \
                               (ch & 3) * 16 + (tq & 3) * 4]) =                \
                make_uint2(u0, u1);                                            \
        }                                                                      \
        s0 += __shfl_xor(s0, 8); s0 += __shfl_xor(s0, 16); s0 += __shfl_xor(s0, 32); \
        s1 += __shfl_xor(s1, 8); s1 += __shfl_xor(s1, 16); s1 += __shfl_xor(s1, 32); \
        s2 += __shfl_xor(s2, 8); s2 += __shfl_xor(s2, 16); s2 += __shfl_xor(s2, 32); \
        s3 += __shfl_xor(s3, 8); s3 += __shfl_xor(s3, 16); s3 += __shfl_xor(s3, 32); \
        if (l < 8) *(float4*)&swsq[w * 32 + tq * 4] = make_float4(s0, s1, s2, s3); \
    }

    // prologue: stage chunk 0
    STAGE_LOAD(0);
    STAGE_WRITE(0);
    __syncthreads();

    #pragma unroll
    for (int ct = 0; ct < NCH; ++ct) {
        const int p = ct & 1;

        // ---- phase 1: issue next-chunk loads, then MFMA-A (S = X·Cw^T) ----
        if (ct < NCH - 1) STAGE_LOAD(ct + 1);

        f32x4 acca = (f32x4){0.f, 0.f, 0.f, 0.f};
        {
            u32 abase = xtbase + p * 16384 +
                        (4 * (l >> 4) + (w & 1)) * 128 + (l & 15) * 8;
            u32x2 rr[16];
            #pragma unroll
            for (int ks = 0; ks < 8; ++ks) {
                asm volatile("ds_read_b64_tr_b16 %0, %1 offset:%2"
                             : "=v"(rr[2 * ks]) : "v"(abase), "i"(ks * 2048));
                asm volatile("ds_read_b64_tr_b16 %0, %1 offset:%2"
                             : "=v"(rr[2 * ks + 1]) : "v"(abase), "i"(ks * 2048 + 256));
            }
            asm volatile("s_waitcnt lgkmcnt(0)");
            __builtin_amdgcn_sched_barrier(0);
            #pragma unroll
            for (int ks = 0; ks < 8; ++ks) {
                union { uint4 u; f16x8 h; } af;
                af.u = make_uint4(rr[2 * ks].x, rr[2 * ks].y, rr[2 * ks + 1].x, rr[2 * ks + 1].y);
                acca = __builtin_amdgcn_mfma_f32_16x16x32_f16(af.h, cwf[ks], acca, 0, 0, 0);
            }
        }
        {   // write S tile: row tok = (w&1)*16 + (l>>4)*4 + r, col k = (w>>1)*16 + (l&15)
            int trow = (w & 1) * 16 + (l >> 4) * 4;
            int kcol = (w >> 1) * 16 + (l & 15);
            #pragma unroll
            for (int r = 0; r < 4; ++r)
                sc[(trow + r) * 33 + kcol] = acca[r];
        }
        __syncthreads();  // bar A: sc + (prev-phase) xt stable

        // ---- phase 2: softmax (all lanes: t = w*8 + (l>>3), k-quad s = l&7) ----
        {
            int t = w * 8 + (l >> 3), s = l & 7;
            float xq = swsq[t] + swsq[32 + t] + swsq[64 + t] + swsq[96 + t];
            float lg[4];
            float m = -3.4e38f;
            #pragma unroll
            for (int i = 0; i < 4; ++i) {
                float xcv = sc[t * 33 + s * 4 + i];
                lg[i] = fmaf(Ak[i], xq, Bk[i]) + Pk[i] * xcv;
                m = fmaxf(m, lg[i]);
            }
            m = fmaxf(m, __shfl_xor(m, 1));
            m = fmaxf(m, __shfl_xor(m, 2));
            m = fmaxf(m, __shfl_xor(m, 4));
            float e[4], ssum = 0.f;
            #pragma unroll
            for (int i = 0; i < 4; ++i) { e[i] = __expf(lg[i] - m); ssum += e[i]; }
            ssum += __shfl_xor(ssum, 1);
            ssum += __shfl_xor(ssum, 2);
            ssum += __shfl_xor(ssum, 4);
            float r = 1.0f / ssum;
            #pragma unroll
            for (int i = 0; i < 4; ++i) {
                float wv = e[i] * r;
                wsacc[i] += wv;
                union { __fp16 h; u16 u; } cv;
                cv.h = (__fp16)wv;
                w2s[(s * 4 + i) * 40 + t] = cv.u;
            }
        }
        __syncthreads();  // bar B: w2s ready

        // ---- phase 3: MFMA-B (wx += W^T·X) + stage-write next chunk ----
        {
            f16x8 wa[2];
            #pragma unroll
            for (int mt = 0; mt < 2; ++mt)
                wa[mt] = *(const f16x8*)&w2s[(mt * 16 + (l & 15)) * 40 + (l >> 4) * 8];
            #pragma unroll
            for (int nt = 0; nt < 4; ++nt) {
                int ch = (w * 4 + nt) * 16 + (l & 15);
                const f16x8 xb = *(const f16x8*)&xt[p][((ch >> 2) * 2 + (l >> 5)) * 64 +
                                                      (ch & 3) * 16 + ((l >> 4) & 1) * 8];
                #pragma unroll
                for (int mt = 0; mt < 2; ++mt)
                    accb[mt][nt] = __builtin_amdgcn_mfma_f32_16x16x32_f16(wa[mt], xb, accb[mt][nt], 0, 0, 0);
            }
        }
        if (ct < NCH - 1) STAGE_WRITE(p ^ 1);
        __syncthreads();  // bar C
    }

    // ---- epilogue ----
    #pragma unroll
    for (int i = 0; i < 4; ++i) {
        float v = wsacc[i];
        v += __shfl_xor(v, 8); v += __shfl_xor(v, 16); v += __shfl_xor(v, 32);
        if (l < 8)
            atomicAdd(&wsum[b * KK + (l & 7) * 4 + i], v);
    }
    if (use_partials) {
        float* dst = wxp + (size_t)blockIdx.x * 8192;   // per-block tile, plain stores
        #pragma unroll
        for (int mt = 0; mt < 2; ++mt)
            #pragma unroll
            for (int nt = 0; nt < 4; ++nt)
                #pragma unroll
                for (int r = 0; r < 4; ++r) {
                    int k  = mt * 16 + (l >> 4) * 4 + r;
                    int ch = (w * 4 + nt) * 16 + (l & 15);
                    dst[k * 256 + ch] = accb[mt][nt][r];
                }
    } else {
        #pragma unroll
        for (int mt = 0; mt < 2; ++mt)
            #pragma unroll
            for (int nt = 0; nt < 4; ++nt)
                #pragma unroll
                for (int r = 0; r < 4; ++r) {
                    int k  = mt * 16 + (l >> 4) * 4 + r;
                    int ch = (w * 4 + nt) * 16 + (l & 15);
                    atomicAdd(&wxp[(size_t)b * 8192 + k * 256 + ch], accb[mt][nt][r]);
                }
    }
}

// ---------------- finalize (partial path): out = sum_blk wxp - wsum*c ----------------
__global__ void enc_final_part(const float* __restrict__ wxp, const float* __restrict__ wsum,
                               const float* __restrict__ cw, float* __restrict__ out) {
    int i = blockIdx.x * 256 + threadIdx.x;
    int c = i & 255, k = (i >> 8) & 31, b = i >> 13;
    const float* p = wxp + (size_t)b * 32 * 8192 + k * 256 + c;
    float s = 0.f;
    #pragma unroll
    for (int j = 0; j < 32; ++j) s += p[(size_t)j * 8192];
    out[i] = s - wsum[b * 32 + k] * cw[k * 256 + c];
}

// ---------------- finalize (atomic path): out = wx - wsum*c ----------------
__global__ void enc_final_atomic(const float* __restrict__ wx, const float* __restrict__ wsum,
                                 const float* __restrict__ cw, float* __restrict__ out) {
    int i = blockIdx.x * 256 + threadIdx.x;
    int c = i & 255, k = (i >> 8) & 31, b = i >> 13;
    out[i] = wx[i] - wsum[b * 32 + k] * cw[k * 256 + c];
}

extern "C" void kernel_launch(void* const* d_in, const int* in_sizes, int n_in,
                              void* d_out, int out_size, void* d_ws, size_t ws_size,
                              hipStream_t stream) {
    (void)in_sizes; (void)n_in; (void)out_size;
    const float* x     = (const float*)d_in[0];
    const float* cw    = (const float*)d_in[1];
    const float* scale = (const float*)d_in[2];
    float* out = (float*)d_out;
    float* wsf = (float*)d_ws;

    const size_t need = (size_t)(8388608 + 1024 + 128 + 4096) * 4;
    const int use_partials = (ws_size >= need) ? 1 : 0;

    float *wxp, *wsum, *abp4;
    u16* cwh;
    if (use_partials) {
        wxp  = wsf;                        // 8388608 f32 (1024 block tiles)
        wsum = wsf + 8388608;              // 1024 f32
        abp4 = wsf + 8389632;              // 128 f32
        cwh  = (u16*)(wsf + 8389760);      // 8192 u16
        (void)hipMemsetAsync(wsum, 0, 1024 * sizeof(float), stream);
    } else {
        wxp  = wsf;                        // 262144 f32
        wsum = wsf + 262144;               // 1024 f32
        abp4 = wsf + 263168;               // 128 f32
        cwh  = (u16*)(wsf + 263296);       // 8192 u16
        (void)hipMemsetAsync(d_ws, 0, 263168 * sizeof(float), stream);
    }

    hipLaunchKernelGGL(enc_prep, dim3(1),    dim3(256), 0, stream, cw, scale, abp4, cwh);
    hipLaunchKernelGGL(enc_main, dim3(1024), dim3(256), 0, stream, x, cwh, abp4, wxp, wsum, use_partials);
    if (use_partials)
        hipLaunchKernelGGL(enc_final_part,   dim3(1024), dim3(256), 0, stream, wxp, wsum, cw, out);
    else
        hipLaunchKernelGGL(enc_final_atomic, dim3(1024), dim3(256), 0, stream, wxp, wsum, cw, out);
}